// Round 1
// baseline (9607.464 us; speedup 1.0000x reference)
//
#include <hip/hip_runtime.h>
#include <hip/hip_bf16.h>
#include <stdint.h>

// Problem dims
#define Bz 64
#define Tz 512
#define Iz 256
#define Hz 256
#define G4z 1024
#define YSZ (Bz*Tz*Hz)          // 8388608

typedef __bf16 bf16;
typedef float  f32x4  __attribute__((ext_vector_type(4)));
typedef __bf16 bf16x8 __attribute__((ext_vector_type(8)));
typedef __bf16 bf16x4 __attribute__((ext_vector_type(4)));

// ---------------- workspace layout ----------------
#define XP_OFF  0u                      // float [32768][1024]  = 134217728 B
#define XB_OFF  134217728u              // bf16  [32768][256]   = 16777216 B
#define WI_OFF  150994944u              // bf16  [1024][256]    = 524288 B
#define HG_OFF  151519232u              // float [8][8][256]    = 65536 B
#define CTR_OFF 151584768u              // uint  [8][512]       = 16384 B
#define CTR_BYTES 16384u

// ---------------- fp32 -> bf16 convert ----------------
__global__ __launch_bounds__(256) void cvt_f32_bf16(const float* __restrict__ in,
                                                    bf16* __restrict__ out, int n4) {
  int i = blockIdx.x * blockDim.x + threadIdx.x;
  if (i >= n4) return;
  float4 v = reinterpret_cast<const float4*>(in)[i];
  bf16x4 o = {(__bf16)v.x, (__bf16)v.y, (__bf16)v.z, (__bf16)v.w};
  *reinterpret_cast<bf16x4*>(out + (size_t)i*4) = o;
}

// ---------------- x_proj GEMM: [M=32768,K=256] @ [N=1024,K=256]^T + bias ----------------
__global__ __launch_bounds__(256) void xproj_gemm(const bf16* __restrict__ A,
                                                  const bf16* __restrict__ Bw,
                                                  const float* __restrict__ b_ih,
                                                  const float* __restrict__ b_hh,
                                                  float* __restrict__ C) {
  constexpr int K = 256, N = 1024;
  __shared__ __align__(16) bf16 As[128*32];
  __shared__ __align__(16) bf16 Bs[128*32];
  __shared__ float bias_s[128];
  const int bm = blockIdx.x >> 3;
  const int bn = blockIdx.x & 7;
  const int m0 = bm * 128, n0 = bn * 128;
  const int tid = threadIdx.x;
  if (tid < 128) bias_s[tid] = b_ih[n0 + tid] + b_hh[n0 + tid];
  const int w = tid >> 6, lane = tid & 63;
  const int wm = w >> 1, wn = w & 1;
  const int lr = lane & 15, lk = lane >> 4;
  f32x4 acc[4][4] = {};
  for (int kt = 0; kt < 8; ++kt) {
    // stage 128x32 bf16 tiles (reg-staged, 16B-chunk XOR swizzle)
#pragma unroll
    for (int p = 0; p < 2; ++p) {
      int elem = p * 256 + tid;
      int row = elem >> 2, c = elem & 3;
      uint4 va = *reinterpret_cast<const uint4*>(A + (size_t)(m0 + row) * K + kt*32 + c*8);
      *reinterpret_cast<uint4*>((char*)As + row*64 + ((c ^ (row & 3)) * 16)) = va;
      uint4 vb = *reinterpret_cast<const uint4*>(Bw + (size_t)(n0 + row) * K + kt*32 + c*8);
      *reinterpret_cast<uint4*>((char*)Bs + row*64 + ((c ^ (row & 3)) * 16)) = vb;
    }
    __syncthreads();
    bf16x8 fa[4], fb[4];
#pragma unroll
    for (int f = 0; f < 4; ++f) {
      int ra = wm*64 + f*16 + lr;
      fa[f] = *reinterpret_cast<const bf16x8*>((char*)As + ra*64 + ((lk ^ (ra & 3)) * 16));
      int rb = wn*64 + f*16 + lr;
      fb[f] = *reinterpret_cast<const bf16x8*>((char*)Bs + rb*64 + ((lk ^ (rb & 3)) * 16));
    }
#pragma unroll
    for (int fi = 0; fi < 4; ++fi)
#pragma unroll
      for (int fj = 0; fj < 4; ++fj)
        acc[fi][fj] = __builtin_amdgcn_mfma_f32_16x16x32_bf16(fa[fi], fb[fj], acc[fi][fj], 0, 0, 0);
    __syncthreads();
  }
  // epilogue: D row=(lane>>4)*4+reg, col=lane&15  [m89-verified layout]
#pragma unroll
  for (int fi = 0; fi < 4; ++fi)
#pragma unroll
    for (int fj = 0; fj < 4; ++fj) {
      int col = n0 + wn*64 + fj*16 + lr;
      float bias = bias_s[wn*64 + fj*16 + lr];
#pragma unroll
      for (int v = 0; v < 4; ++v) {
        int row = m0 + wm*64 + fi*16 + lk*4 + v;
        C[(size_t)row * N + col] = acc[fi][fj][v] + bias;
      }
    }
}

// ---------------- recurrence ----------------
// 8 groups (8 batches each) x 16 j-blocks (16 h-outputs each) = 128 blocks.
// Group members share blockIdx%8 -> same XCD under round-robin dispatch.
#define NJ 16

__global__ __launch_bounds__(256) void lstm_rec(const float* __restrict__ xp,
                                                const float* __restrict__ Whh,
                                                float* __restrict__ out,
                                                float* __restrict__ h_glob,
                                                unsigned int* __restrict__ ctr) {
  __shared__ __align__(16) float Wl[64 * 256];      // 64KB, 16B-chunk XOR swizzled
  __shared__ __align__(16) float h_s[8 * 256];      // 8KB
  __shared__ float red[4][8][65];
  __shared__ float xp_s[512];
  __shared__ float c_s[8][16];
  const int tid = threadIdx.x;
  const int g  = blockIdx.x & 7;
  const int jb = blockIdx.x >> 3;

  // load W slice (rows G*256 + jb*16 + nn), swizzled
  for (int idx = tid; idx < 64 * 64; idx += 256) {
    int r = idx >> 6, c = idx & 63;
    int G = r >> 4, nn = r & 15;
    uint4 v = *reinterpret_cast<const uint4*>(Whh + (size_t)(G*256 + jb*16 + nn) * 256 + c*4);
    *reinterpret_cast<uint4*>((char*)Wl + r*1024 + ((c ^ (r & 7)) * 16)) = v;
  }
  for (int idx = tid; idx < 8 * 256; idx += 256) h_s[idx] = 0.f;
  if (tid < 128) c_s[tid >> 4][tid & 15] = 0.f;
  __syncthreads();

  const int r_ = tid & 63, kc = tid >> 6;
  const int swz = r_ & 7;
  unsigned int* myctr = ctr + g * Tz;

  for (int t = 0; t < Tz; ++t) {
    // prefetch this step's x_proj slice (hidden under FMA phase)
    float xpv0, xpv1;
    {
      int b = tid >> 6, r = tid & 63;
      xpv0 = xp[((size_t)(g*8 + b) * Tz + t) * 1024 + (r >> 4) * 256 + jb*16 + (r & 15)];
      int i1 = tid + 256;
      int b1 = i1 >> 6, r1 = i1 & 63;
      xpv1 = xp[((size_t)(g*8 + b1) * Tz + t) * 1024 + (r1 >> 4) * 256 + jb*16 + (r1 & 15)];
    }
    // gate partials: thread (r_, kc) does rows r_ over k-window kc*64..+64 for 8 batches
    float acc[8] = {0.f,0.f,0.f,0.f,0.f,0.f,0.f,0.f};
    const char* wbase = (const char*)Wl + r_ * 1024;
#pragma unroll 4
    for (int cc = 0; cc < 16; ++cc) {
      int ch = kc * 16 + cc;
      float4 wv = *reinterpret_cast<const float4*>(wbase + ((ch ^ swz) * 16));
#pragma unroll
      for (int b = 0; b < 8; ++b) {
        float4 hv = *reinterpret_cast<const float4*>(&h_s[b*256 + kc*64 + cc*4]);
        float a = acc[b];
        a = fmaf(wv.x, hv.x, a);
        a = fmaf(wv.y, hv.y, a);
        a = fmaf(wv.z, hv.z, a);
        a = fmaf(wv.w, hv.w, a);
        acc[b] = a;
      }
    }
    xp_s[tid] = xpv0;
    xp_s[tid + 256] = xpv1;
#pragma unroll
    for (int b = 0; b < 8; ++b) red[kc][b][r_] = acc[b];
    __syncthreads();

    // reduce + nonlinearity: thread (bb, nn), tid<128
    if (tid < 128) {
      int bb = tid >> 4, nn = tid & 15;
      float s[4];
#pragma unroll
      for (int G = 0; G < 4; ++G) {
        int r = G*16 + nn;
        float v = xp_s[bb*64 + r];
#pragma unroll
        for (int k2 = 0; k2 < 4; ++k2) v += red[k2][bb][r];
        s[G] = v;
      }
      float ig = 1.f / (1.f + __expf(-s[0]));
      float fg = 1.f / (1.f + __expf(-s[1]));
      float gg = tanhf(s[2]);
      float og = 1.f / (1.f + __expf(-s[3]));
      float cnew = fg * c_s[bb][nn] + ig * gg;
      c_s[bb][nn] = cnew;
      float hnew = og * tanhf(cnew);
      h_glob[(size_t)g*2048 + bb*256 + jb*16 + nn] = hnew;
      out[((size_t)(g*8 + bb) * Tz + t) * 256 + jb*16 + nn] = hnew;
      if (t == Tz - 1) {
        out[(size_t)YSZ + (g*8 + bb)*256 + jb*16 + nn] = hnew;
        out[(size_t)YSZ + 16384 + (g*8 + bb)*256 + jb*16 + nn] = cnew;
      }
    }
    if (t == Tz - 1) break;

    // group barrier: release h slice, wait for all NJ peers
    __threadfence();
    __syncthreads();
    if (tid == 0) {
      atomicAdd(myctr + t, 1u);
      while (__hip_atomic_load(myctr + t, __ATOMIC_RELAXED, __HIP_MEMORY_SCOPE_AGENT) < NJ) {
        __builtin_amdgcn_s_sleep(1);
      }
    }
    __syncthreads();
    __threadfence();   // acquire: invalidate caches before reading peers' h
    {
      int base = tid * 8;
      float4 v0 = *reinterpret_cast<const float4*>(h_glob + (size_t)g*2048 + base);
      float4 v1 = *reinterpret_cast<const float4*>(h_glob + (size_t)g*2048 + base + 4);
      *reinterpret_cast<float4*>(&h_s[base]) = v0;
      *reinterpret_cast<float4*>(&h_s[base + 4]) = v1;
    }
    __syncthreads();
  }
}

extern "C" void kernel_launch(void* const* d_in, const int* in_sizes, int n_in,
                              void* d_out, int out_size, void* d_ws, size_t ws_size,
                              hipStream_t stream) {
  const float* x    = (const float*)d_in[0];
  const float* W_ih = (const float*)d_in[1];
  const float* W_hh = (const float*)d_in[2];
  const float* b_ih = (const float*)d_in[3];
  const float* b_hh = (const float*)d_in[4];
  float* out = (float*)d_out;
  char* ws = (char*)d_ws;

  float*    xp    = (float*)(ws + XP_OFF);
  bf16*     xb    = (bf16*) (ws + XB_OFF);
  bf16*     wib   = (bf16*) (ws + WI_OFF);
  float*    hglob = (float*)(ws + HG_OFF);
  unsigned* ctr   = (unsigned*)(ws + CTR_OFF);

  hipMemsetAsync(ctr, 0, CTR_BYTES, stream);
  cvt_f32_bf16<<<8192, 256, 0, stream>>>(x, xb, (Bz*Tz*Iz) / 4);
  cvt_f32_bf16<<<256, 256, 0, stream>>>(W_ih, wib, (G4z*Iz) / 4);
  xproj_gemm<<<2048, 256, 0, stream>>>(xb, wib, b_ih, b_hh, xp);
  lstm_rec<<<128, 256, 0, stream>>>(xp, W_hh, out, hglob, ctr);
}

// Round 2
// 2504.043 us; speedup vs baseline: 3.8368x; 3.8368x over previous
//
#include <hip/hip_runtime.h>
#include <hip/hip_bf16.h>
#include <stdint.h>

// Problem dims
#define Bz 64
#define Tz 512
#define Iz 256
#define Hz 256
#define G4z 1024
#define YSZ (Bz*Tz*Hz)          // 8388608

typedef __bf16 bf16;
typedef float  f32x4  __attribute__((ext_vector_type(4)));
typedef __bf16 bf16x8 __attribute__((ext_vector_type(8)));
typedef __bf16 bf16x4 __attribute__((ext_vector_type(4)));

// ---------------- workspace layout ----------------
#define XP_OFF  0u                      // float [32768][1024]  = 134217728 B
#define XB_OFF  134217728u              // bf16  [32768][256]   = 16777216 B
#define WI_OFF  150994944u              // bf16  [1024][256]    = 524288 B
#define HG_OFF  151519232u              // float [8][8][256]    = 65536 B
#define CTR_OFF 151584768u              // uint  [8][512]       = 16384 B
#define CTR_BYTES 16384u

// ---------------- fp32 -> bf16 convert ----------------
__global__ __launch_bounds__(256) void cvt_f32_bf16(const float* __restrict__ in,
                                                    bf16* __restrict__ out, int n4) {
  int i = blockIdx.x * blockDim.x + threadIdx.x;
  if (i >= n4) return;
  float4 v = reinterpret_cast<const float4*>(in)[i];
  bf16x4 o = {(__bf16)v.x, (__bf16)v.y, (__bf16)v.z, (__bf16)v.w};
  *reinterpret_cast<bf16x4*>(out + (size_t)i*4) = o;
}

// ---------------- x_proj GEMM: [M=32768,K=256] @ [N=1024,K=256]^T + bias ----------------
__global__ __launch_bounds__(256) void xproj_gemm(const bf16* __restrict__ A,
                                                  const bf16* __restrict__ Bw,
                                                  const float* __restrict__ b_ih,
                                                  const float* __restrict__ b_hh,
                                                  float* __restrict__ C) {
  constexpr int K = 256, N = 1024;
  __shared__ __align__(16) bf16 As[128*32];
  __shared__ __align__(16) bf16 Bs[128*32];
  __shared__ float bias_s[128];
  const int bm = blockIdx.x >> 3;
  const int bn = blockIdx.x & 7;
  const int m0 = bm * 128, n0 = bn * 128;
  const int tid = threadIdx.x;
  if (tid < 128) bias_s[tid] = b_ih[n0 + tid] + b_hh[n0 + tid];
  const int w = tid >> 6, lane = tid & 63;
  const int wm = w >> 1, wn = w & 1;
  const int lr = lane & 15, lk = lane >> 4;
  f32x4 acc[4][4] = {};
  for (int kt = 0; kt < 8; ++kt) {
    // stage 128x32 bf16 tiles (reg-staged, 16B-chunk XOR swizzle)
#pragma unroll
    for (int p = 0; p < 2; ++p) {
      int elem = p * 256 + tid;
      int row = elem >> 2, c = elem & 3;
      uint4 va = *reinterpret_cast<const uint4*>(A + (size_t)(m0 + row) * K + kt*32 + c*8);
      *reinterpret_cast<uint4*>((char*)As + row*64 + ((c ^ (row & 3)) * 16)) = va;
      uint4 vb = *reinterpret_cast<const uint4*>(Bw + (size_t)(n0 + row) * K + kt*32 + c*8);
      *reinterpret_cast<uint4*>((char*)Bs + row*64 + ((c ^ (row & 3)) * 16)) = vb;
    }
    __syncthreads();
    bf16x8 fa[4], fb[4];
#pragma unroll
    for (int f = 0; f < 4; ++f) {
      int ra = wm*64 + f*16 + lr;
      fa[f] = *reinterpret_cast<const bf16x8*>((char*)As + ra*64 + ((lk ^ (ra & 3)) * 16));
      int rb = wn*64 + f*16 + lr;
      fb[f] = *reinterpret_cast<const bf16x8*>((char*)Bs + rb*64 + ((lk ^ (rb & 3)) * 16));
    }
#pragma unroll
    for (int fi = 0; fi < 4; ++fi)
#pragma unroll
      for (int fj = 0; fj < 4; ++fj)
        acc[fi][fj] = __builtin_amdgcn_mfma_f32_16x16x32_bf16(fa[fi], fb[fj], acc[fi][fj], 0, 0, 0);
    __syncthreads();
  }
  // epilogue: D row=(lane>>4)*4+reg, col=lane&15  [m89-verified layout]
#pragma unroll
  for (int fi = 0; fi < 4; ++fi)
#pragma unroll
    for (int fj = 0; fj < 4; ++fj) {
      int col = n0 + wn*64 + fj*16 + lr;
      float bias = bias_s[wn*64 + fj*16 + lr];
#pragma unroll
      for (int v = 0; v < 4; ++v) {
        int row = m0 + wm*64 + fi*16 + lk*4 + v;
        C[(size_t)row * N + col] = acc[fi][fj][v] + bias;
      }
    }
}

// ---------------- recurrence ----------------
// 8 groups (8 batches each) x 16 j-blocks (16 h-outputs each) = 128 blocks.
// Cross-block communication is done ONLY through cache-bypassing (agent-scope
// relaxed atomic) loads/stores -> no fences, no L2 writeback/invalidate.
#define NJ 16

__global__ __launch_bounds__(256) void lstm_rec(const float* __restrict__ xp,
                                                const float* __restrict__ Whh,
                                                float* __restrict__ out,
                                                float* __restrict__ h_glob,
                                                unsigned int* __restrict__ ctr) {
  __shared__ __align__(16) float Wl[64 * 256];      // 64KB, 16B-chunk XOR swizzled
  __shared__ __align__(16) float h_s[8 * 256];      // 8KB
  __shared__ float red[4][8][65];
  __shared__ float xp_s[512];
  __shared__ float c_s[8][16];
  const int tid = threadIdx.x;
  const int g  = blockIdx.x & 7;
  const int jb = blockIdx.x >> 3;

  // load W slice (rows G*256 + jb*16 + nn), swizzled
  for (int idx = tid; idx < 64 * 64; idx += 256) {
    int r = idx >> 6, c = idx & 63;
    int G = r >> 4, nn = r & 15;
    uint4 v = *reinterpret_cast<const uint4*>(Whh + (size_t)(G*256 + jb*16 + nn) * 256 + c*4);
    *reinterpret_cast<uint4*>((char*)Wl + r*1024 + ((c ^ (r & 7)) * 16)) = v;
  }
  for (int idx = tid; idx < 8 * 256; idx += 256) h_s[idx] = 0.f;
  if (tid < 128) c_s[tid >> 4][tid & 15] = 0.f;
  __syncthreads();

  const int r_ = tid & 63, kc = tid >> 6;
  const int swz = r_ & 7;
  unsigned int* myctr = ctr + g * Tz;
  float* hg = h_glob + (size_t)g * 2048;

  for (int t = 0; t < Tz; ++t) {
    // prefetch this step's x_proj slice (hidden under FMA phase)
    float xpv0, xpv1;
    {
      int b = tid >> 6, r = tid & 63;
      xpv0 = xp[((size_t)(g*8 + b) * Tz + t) * 1024 + (r >> 4) * 256 + jb*16 + (r & 15)];
      int i1 = tid + 256;
      int b1 = i1 >> 6, r1 = i1 & 63;
      xpv1 = xp[((size_t)(g*8 + b1) * Tz + t) * 1024 + (r1 >> 4) * 256 + jb*16 + (r1 & 15)];
    }
    // gate partials: thread (r_, kc) does rows r_ over k-window kc*64..+64 for 8 batches
    float acc[8] = {0.f,0.f,0.f,0.f,0.f,0.f,0.f,0.f};
    const char* wbase = (const char*)Wl + r_ * 1024;
#pragma unroll 4
    for (int cc = 0; cc < 16; ++cc) {
      int ch = kc * 16 + cc;
      float4 wv = *reinterpret_cast<const float4*>(wbase + ((ch ^ swz) * 16));
#pragma unroll
      for (int b = 0; b < 8; ++b) {
        float4 hv = *reinterpret_cast<const float4*>(&h_s[b*256 + kc*64 + cc*4]);
        float a = acc[b];
        a = fmaf(wv.x, hv.x, a);
        a = fmaf(wv.y, hv.y, a);
        a = fmaf(wv.z, hv.z, a);
        a = fmaf(wv.w, hv.w, a);
        acc[b] = a;
      }
    }
    xp_s[tid] = xpv0;
    xp_s[tid + 256] = xpv1;
#pragma unroll
    for (int b = 0; b < 8; ++b) red[kc][b][r_] = acc[b];
    __syncthreads();

    // reduce + nonlinearity: thread (bb, nn), tid<128
    if (tid < 128) {
      int bb = tid >> 4, nn = tid & 15;
      float s[4];
#pragma unroll
      for (int G = 0; G < 4; ++G) {
        int r = G*16 + nn;
        float v = xp_s[bb*64 + r];
#pragma unroll
        for (int k2 = 0; k2 < 4; ++k2) v += red[k2][bb][r];
        s[G] = v;
      }
      float ig = 1.f / (1.f + __expf(-s[0]));
      float fg = 1.f / (1.f + __expf(-s[1]));
      float gg = tanhf(s[2]);
      float og = 1.f / (1.f + __expf(-s[3]));
      float cnew = fg * c_s[bb][nn] + ig * gg;
      c_s[bb][nn] = cnew;
      float hnew = og * tanhf(cnew);
      // cache-bypassing store -> coherent point, no fence needed
      __hip_atomic_store(&hg[bb*256 + jb*16 + nn], hnew,
                         __ATOMIC_RELAXED, __HIP_MEMORY_SCOPE_AGENT);
      out[((size_t)(g*8 + bb) * Tz + t) * 256 + jb*16 + nn] = hnew;
      if (t == Tz - 1) {
        out[(size_t)YSZ + (g*8 + bb)*256 + jb*16 + nn] = hnew;
        out[(size_t)YSZ + 16384 + (g*8 + bb)*256 + jb*16 + nn] = cnew;
      }
    }
    if (t == Tz - 1) break;

    // group barrier. __syncthreads drains each wave's outstanding vmem
    // (compiler emits s_waitcnt vmcnt(0) before s_barrier), so the agent-scope
    // h stores above are at the coherent point before tid0 signals arrival.
    __syncthreads();
    if (tid == 0) {
      __hip_atomic_fetch_add(myctr + t, 1u, __ATOMIC_RELAXED, __HIP_MEMORY_SCOPE_AGENT);
      while (__hip_atomic_load(myctr + t, __ATOMIC_RELAXED, __HIP_MEMORY_SCOPE_AGENT) < NJ) {
        __builtin_amdgcn_s_sleep(1);
      }
    }
    __syncthreads();
    // read peers' h via cache-bypassing loads (read coherent point directly)
    {
      int base = tid * 8;
      float v0 = __hip_atomic_load(hg + base + 0, __ATOMIC_RELAXED, __HIP_MEMORY_SCOPE_AGENT);
      float v1 = __hip_atomic_load(hg + base + 1, __ATOMIC_RELAXED, __HIP_MEMORY_SCOPE_AGENT);
      float v2 = __hip_atomic_load(hg + base + 2, __ATOMIC_RELAXED, __HIP_MEMORY_SCOPE_AGENT);
      float v3 = __hip_atomic_load(hg + base + 3, __ATOMIC_RELAXED, __HIP_MEMORY_SCOPE_AGENT);
      float v4 = __hip_atomic_load(hg + base + 4, __ATOMIC_RELAXED, __HIP_MEMORY_SCOPE_AGENT);
      float v5 = __hip_atomic_load(hg + base + 5, __ATOMIC_RELAXED, __HIP_MEMORY_SCOPE_AGENT);
      float v6 = __hip_atomic_load(hg + base + 6, __ATOMIC_RELAXED, __HIP_MEMORY_SCOPE_AGENT);
      float v7 = __hip_atomic_load(hg + base + 7, __ATOMIC_RELAXED, __HIP_MEMORY_SCOPE_AGENT);
      h_s[base + 0] = v0;
      h_s[base + 1] = v1;
      h_s[base + 2] = v2;
      h_s[base + 3] = v3;
      h_s[base + 4] = v4;
      h_s[base + 5] = v5;
      h_s[base + 6] = v6;
      h_s[base + 7] = v7;
    }
    __syncthreads();
  }
}

extern "C" void kernel_launch(void* const* d_in, const int* in_sizes, int n_in,
                              void* d_out, int out_size, void* d_ws, size_t ws_size,
                              hipStream_t stream) {
  const float* x    = (const float*)d_in[0];
  const float* W_ih = (const float*)d_in[1];
  const float* W_hh = (const float*)d_in[2];
  const float* b_ih = (const float*)d_in[3];
  const float* b_hh = (const float*)d_in[4];
  float* out = (float*)d_out;
  char* ws = (char*)d_ws;

  float*    xp    = (float*)(ws + XP_OFF);
  bf16*     xb    = (bf16*) (ws + XB_OFF);
  bf16*     wib   = (bf16*) (ws + WI_OFF);
  float*    hglob = (float*)(ws + HG_OFF);
  unsigned* ctr   = (unsigned*)(ws + CTR_OFF);

  hipMemsetAsync(ctr, 0, CTR_BYTES, stream);
  cvt_f32_bf16<<<8192, 256, 0, stream>>>(x, xb, (Bz*Tz*Iz) / 4);
  cvt_f32_bf16<<<256, 256, 0, stream>>>(W_ih, wib, (G4z*Iz) / 4);
  xproj_gemm<<<2048, 256, 0, stream>>>(xb, wib, b_ih, b_hh, xp);
  lstm_rec<<<128, 256, 0, stream>>>(xp, W_hh, out, hglob, ctr);
}

// Round 3
// 2116.722 us; speedup vs baseline: 4.5388x; 1.1830x over previous
//
#include <hip/hip_runtime.h>
#include <hip/hip_bf16.h>
#include <stdint.h>

// Problem dims
#define Bz 64
#define Tz 512
#define Iz 256
#define Hz 256
#define G4z 1024
#define YSZ (Bz*Tz*Hz)          // 8388608

typedef __bf16 bf16;
typedef float  f32x4  __attribute__((ext_vector_type(4)));
typedef __bf16 bf16x8 __attribute__((ext_vector_type(8)));
typedef __bf16 bf16x4 __attribute__((ext_vector_type(4)));

// ---------------- workspace layout ----------------
#define XP_OFF  0u                      // float [32768][1024]  = 134217728 B
#define XB_OFF  134217728u              // bf16  [32768][256]   = 16777216 B
#define WI_OFF  150994944u              // bf16  [1024][256]    = 524288 B
#define HG_OFF  151519232u              // float [4][16][256]   = 65536 B
#define CTR_OFF 151584768u              // uint  [4][512]       = 8192 B
#define CTR_BYTES 8192u

// ---------------- fp32 -> bf16 convert ----------------
__global__ __launch_bounds__(256) void cvt_f32_bf16(const float* __restrict__ in,
                                                    bf16* __restrict__ out, int n4) {
  int i = blockIdx.x * blockDim.x + threadIdx.x;
  if (i >= n4) return;
  float4 v = reinterpret_cast<const float4*>(in)[i];
  bf16x4 o = {(__bf16)v.x, (__bf16)v.y, (__bf16)v.z, (__bf16)v.w};
  *reinterpret_cast<bf16x4*>(out + (size_t)i*4) = o;
}

// ---------------- x_proj GEMM: [M=32768,K=256] @ [N=1024,K=256]^T + bias ----------------
__global__ __launch_bounds__(256) void xproj_gemm(const bf16* __restrict__ A,
                                                  const bf16* __restrict__ Bw,
                                                  const float* __restrict__ b_ih,
                                                  const float* __restrict__ b_hh,
                                                  float* __restrict__ C) {
  constexpr int K = 256, N = 1024;
  __shared__ __align__(16) bf16 As[128*32];
  __shared__ __align__(16) bf16 Bs[128*32];
  __shared__ float bias_s[128];
  const int bm = blockIdx.x >> 3;
  const int bn = blockIdx.x & 7;
  const int m0 = bm * 128, n0 = bn * 128;
  const int tid = threadIdx.x;
  if (tid < 128) bias_s[tid] = b_ih[n0 + tid] + b_hh[n0 + tid];
  const int w = tid >> 6, lane = tid & 63;
  const int wm = w >> 1, wn = w & 1;
  const int lr = lane & 15, lk = lane >> 4;
  f32x4 acc[4][4] = {};
  for (int kt = 0; kt < 8; ++kt) {
#pragma unroll
    for (int p = 0; p < 2; ++p) {
      int elem = p * 256 + tid;
      int row = elem >> 2, c = elem & 3;
      uint4 va = *reinterpret_cast<const uint4*>(A + (size_t)(m0 + row) * K + kt*32 + c*8);
      *reinterpret_cast<uint4*>((char*)As + row*64 + ((c ^ (row & 3)) * 16)) = va;
      uint4 vb = *reinterpret_cast<const uint4*>(Bw + (size_t)(n0 + row) * K + kt*32 + c*8);
      *reinterpret_cast<uint4*>((char*)Bs + row*64 + ((c ^ (row & 3)) * 16)) = vb;
    }
    __syncthreads();
    bf16x8 fa[4], fb[4];
#pragma unroll
    for (int f = 0; f < 4; ++f) {
      int ra = wm*64 + f*16 + lr;
      fa[f] = *reinterpret_cast<const bf16x8*>((char*)As + ra*64 + ((lk ^ (ra & 3)) * 16));
      int rb = wn*64 + f*16 + lr;
      fb[f] = *reinterpret_cast<const bf16x8*>((char*)Bs + rb*64 + ((lk ^ (rb & 3)) * 16));
    }
#pragma unroll
    for (int fi = 0; fi < 4; ++fi)
#pragma unroll
      for (int fj = 0; fj < 4; ++fj)
        acc[fi][fj] = __builtin_amdgcn_mfma_f32_16x16x32_bf16(fa[fi], fb[fj], acc[fi][fj], 0, 0, 0);
    __syncthreads();
  }
#pragma unroll
  for (int fi = 0; fi < 4; ++fi)
#pragma unroll
    for (int fj = 0; fj < 4; ++fj) {
      int col = n0 + wn*64 + fj*16 + lr;
      float bias = bias_s[wn*64 + fj*16 + lr];
#pragma unroll
      for (int v = 0; v < 4; ++v) {
        int row = m0 + wm*64 + fi*16 + lk*4 + v;
        C[(size_t)row * N + col] = acc[fi][fj][v] + bias;
      }
    }
}

// ---------------- recurrence (MFMA) ----------------
// 4 groups x 16 batches, 4 j-blocks per group (64 h each) = 16 blocks.
// W_hh slice (256 gate rows x 256 k) lives in VGPRs as bf16 fragments.
// Per step: 8 ds_read a-frags + 32 MFMA per wave; gates i,f,g,o for the same
// (batch,h) land in the same lane (acc[G]) -> in-register nonlinearity + c.
#define NJB 4

__device__ __forceinline__ float fast_sigmoid(float x) {
  return __builtin_amdgcn_rcpf(1.f + __expf(-x));
}
__device__ __forceinline__ float fast_tanh(float x) {
  return 1.f - 2.f * __builtin_amdgcn_rcpf(__expf(2.f * x) + 1.f);
}

__global__ __launch_bounds__(256, 1) void lstm_rec(const float* __restrict__ xp,
                                                   const float* __restrict__ Whh,
                                                   float* __restrict__ out,
                                                   float* __restrict__ h_glob,
                                                   unsigned int* __restrict__ ctr) {
  __shared__ __align__(16) bf16 h_s[16 * 256];   // [batch][k], 16B-chunk XOR swizzled
  const int tid = threadIdx.x;
  const int g  = blockIdx.x >> 2;
  const int jb = blockIdx.x & 3;
  const int w  = tid >> 6, l = tid & 63;
  const int lr = l & 15, lk = l >> 4;
  const int hidx = jb*64 + w*16 + lr;            // this lane's h index (n-col)

  // ---- preload W b-frags into VGPRs: bW[G][kk], n = G*256 + hidx, k = kk*32 + lk*8 + e
  bf16x8 bW[4][8];
#pragma unroll
  for (int G = 0; G < 4; ++G)
#pragma unroll
    for (int kk = 0; kk < 8; ++kk) {
      const float* wp = Whh + (size_t)(G*256 + hidx) * 256 + kk*32 + lk*8;
      float4 w0 = *reinterpret_cast<const float4*>(wp);
      float4 w1 = *reinterpret_cast<const float4*>(wp + 4);
      bf16x8 f = {(__bf16)w0.x, (__bf16)w0.y, (__bf16)w0.z, (__bf16)w0.w,
                  (__bf16)w1.x, (__bf16)w1.y, (__bf16)w1.z, (__bf16)w1.w};
      bW[G][kk] = f;
    }

  // zero h_s (h0 = 0)
  {
    uint4 z = {0,0,0,0};
    uint4* p = reinterpret_cast<uint4*>(h_s);
#pragma unroll
    for (int i = 0; i < 2; ++i) p[tid + i*256] = z;
  }

  float c[4] = {0.f, 0.f, 0.f, 0.f};
  // xp prefetch: xpv[G][v] for batch m = lk*4+v, col = G*256 + hidx
  const size_t xcol = (size_t)0 * 0 + hidx;   // col offset built per-G below
  float xpv[4][4];
#pragma unroll
  for (int G = 0; G < 4; ++G)
#pragma unroll
    for (int v = 0; v < 4; ++v)
      xpv[G][v] = xp[((size_t)(g*16 + lk*4 + v) * Tz + 0) * 1024 + G*256 + hidx];

  __syncthreads();

  unsigned int* ctg = ctr + g * Tz;
  float* hg = h_glob + (size_t)g * 4096;       // [16][256] f32
  const int bm_rd = tid >> 4;                   // readback: batch row
  const int k0_rd = (tid & 15) * 16;            // readback: k start

  for (int t = 0; t < Tz; ++t) {
    // a-frags from swizzled h_s: lane reads h[batch=lr][k-chunk kk*4+lk]
    bf16x8 a[8];
#pragma unroll
    for (int kk = 0; kk < 8; ++kk) {
      int ch = kk*4 + lk;
      a[kk] = *reinterpret_cast<const bf16x8*>(
          (const char*)h_s + lr*512 + ((ch ^ (lr & 7)) << 4));
    }
    // init acc from x_proj (includes both biases)
    f32x4 acc[4];
#pragma unroll
    for (int G = 0; G < 4; ++G) {
      acc[G][0] = xpv[G][0]; acc[G][1] = xpv[G][1];
      acc[G][2] = xpv[G][2]; acc[G][3] = xpv[G][3];
    }
    // prefetch next step's xp (latency hidden under MFMA + nonlin + barrier)
    float xpn[4][4];
    {
      int tn = (t < Tz-1) ? t+1 : t;
#pragma unroll
      for (int G = 0; G < 4; ++G)
#pragma unroll
        for (int v = 0; v < 4; ++v)
          xpn[G][v] = xp[((size_t)(g*16 + lk*4 + v) * Tz + tn) * 1024 + G*256 + hidx];
    }
    // gates = xp + h @ W^T : 32 MFMA
#pragma unroll
    for (int kk = 0; kk < 8; ++kk)
#pragma unroll
      for (int G = 0; G < 4; ++G)
        acc[G] = __builtin_amdgcn_mfma_f32_16x16x32_bf16(a[kk], bW[G][kk], acc[G], 0, 0, 0);

    // nonlinearity, fully in-register (batch m = lk*4+v)
    float hv[4];
#pragma unroll
    for (int v = 0; v < 4; ++v) {
      float ig = fast_sigmoid(acc[0][v]);
      float fg = fast_sigmoid(acc[1][v]);
      float gg = fast_tanh(acc[2][v]);
      float og = fast_sigmoid(acc[3][v]);
      float cn = fg * c[v] + ig * gg;
      c[v] = cn;
      hv[v] = og * fast_tanh(cn);
    }
    const int bg0 = g*16 + lk*4;
#pragma unroll
    for (int v = 0; v < 4; ++v) {
      out[((size_t)(bg0 + v) * Tz + t) * 256 + hidx] = hv[v];
      __hip_atomic_store(&hg[(lk*4 + v) * 256 + hidx], hv[v],
                         __ATOMIC_RELAXED, __HIP_MEMORY_SCOPE_AGENT);
    }
    if (t == Tz - 1) {
#pragma unroll
      for (int v = 0; v < 4; ++v) {
        out[(size_t)YSZ + (bg0 + v) * 256 + hidx] = hv[v];
        out[(size_t)YSZ + 16384 + (bg0 + v) * 256 + hidx] = c[v];
      }
      break;
    }

    // group barrier: __syncthreads drains every wave's vmem (stores visible),
    // then one arrival per block; ALL threads poll (no second barrier needed
    // before reading h_glob — each thread reads its own slice).
    __syncthreads();
    if (tid == 0)
      __hip_atomic_fetch_add(ctg + t, 1u, __ATOMIC_RELAXED, __HIP_MEMORY_SCOPE_AGENT);
    while (__hip_atomic_load(ctg + t, __ATOMIC_RELAXED, __HIP_MEMORY_SCOPE_AGENT) < NJB)
      __builtin_amdgcn_s_sleep(2);

    // readback h (cache-bypassing), cvt to bf16, store swizzled into h_s
    {
      float vv[16];
#pragma unroll
      for (int e = 0; e < 16; ++e)
        vv[e] = __hip_atomic_load(&hg[bm_rd*256 + k0_rd + e],
                                  __ATOMIC_RELAXED, __HIP_MEMORY_SCOPE_AGENT);
      bf16x8 p0 = {(__bf16)vv[0], (__bf16)vv[1], (__bf16)vv[2], (__bf16)vv[3],
                   (__bf16)vv[4], (__bf16)vv[5], (__bf16)vv[6], (__bf16)vv[7]};
      bf16x8 p1 = {(__bf16)vv[8], (__bf16)vv[9], (__bf16)vv[10], (__bf16)vv[11],
                   (__bf16)vv[12], (__bf16)vv[13], (__bf16)vv[14], (__bf16)vv[15]};
      int ch0 = (tid & 15) * 2;
      char* dst = (char*)h_s + bm_rd*512;
      *reinterpret_cast<bf16x8*>(dst + ((ch0 ^ (bm_rd & 7)) << 4)) = p0;
      *reinterpret_cast<bf16x8*>(dst + (((ch0+1) ^ (bm_rd & 7)) << 4)) = p1;
    }
#pragma unroll
    for (int G = 0; G < 4; ++G)
#pragma unroll
      for (int v = 0; v < 4; ++v) xpv[G][v] = xpn[G][v];
    __syncthreads();
  }
  (void)xcol;
}

extern "C" void kernel_launch(void* const* d_in, const int* in_sizes, int n_in,
                              void* d_out, int out_size, void* d_ws, size_t ws_size,
                              hipStream_t stream) {
  const float* x    = (const float*)d_in[0];
  const float* W_ih = (const float*)d_in[1];
  const float* W_hh = (const float*)d_in[2];
  const float* b_ih = (const float*)d_in[3];
  const float* b_hh = (const float*)d_in[4];
  float* out = (float*)d_out;
  char* ws = (char*)d_ws;

  float*    xp    = (float*)(ws + XP_OFF);
  bf16*     xb    = (bf16*) (ws + XB_OFF);
  bf16*     wib   = (bf16*) (ws + WI_OFF);
  float*    hglob = (float*)(ws + HG_OFF);
  unsigned* ctr   = (unsigned*)(ws + CTR_OFF);

  hipMemsetAsync(ctr, 0, CTR_BYTES, stream);
  cvt_f32_bf16<<<8192, 256, 0, stream>>>(x, xb, (Bz*Tz*Iz) / 4);
  cvt_f32_bf16<<<256, 256, 0, stream>>>(W_ih, wib, (G4z*Iz) / 4);
  xproj_gemm<<<2048, 256, 0, stream>>>(xb, wib, b_ih, b_hh, xp);
  lstm_rec<<<16, 256, 0, stream>>>(xp, W_hh, out, hglob, ctr);
}

// Round 4
// 2049.844 us; speedup vs baseline: 4.6869x; 1.0326x over previous
//
#include <hip/hip_runtime.h>
#include <hip/hip_bf16.h>
#include <stdint.h>

// Problem dims
#define Bz 64
#define Tz 512
#define Iz 256
#define Hz 256
#define G4z 1024
#define YSZ (Bz*Tz*Hz)          // 8388608

typedef __bf16 bf16;
typedef float  f32x4  __attribute__((ext_vector_type(4)));
typedef __bf16 bf16x8 __attribute__((ext_vector_type(8)));
typedef __bf16 bf16x4 __attribute__((ext_vector_type(4)));

// ---------------- workspace layout ----------------
#define XP_OFF  0u                      // float [32768][1024]  = 134217728 B
#define XB_OFF  134217728u              // bf16  [32768][256]   = 16777216 B
#define WI_OFF  150994944u              // bf16  [1024][256]    = 524288 B

#define SENT 0xFFFFFFFFu                // NaN bit pattern; h is never NaN

// ---------------- fp32 -> bf16 convert ----------------
__global__ __launch_bounds__(256) void cvt_f32_bf16(const float* __restrict__ in,
                                                    bf16* __restrict__ out, int n4) {
  int i = blockIdx.x * blockDim.x + threadIdx.x;
  if (i >= n4) return;
  float4 v = reinterpret_cast<const float4*>(in)[i];
  bf16x4 o = {(__bf16)v.x, (__bf16)v.y, (__bf16)v.z, (__bf16)v.w};
  *reinterpret_cast<bf16x4*>(out + (size_t)i*4) = o;
}

// ---------------- x_proj GEMM: [M=32768,K=256] @ [N=1024,K=256]^T + bias ----------------
__global__ __launch_bounds__(256) void xproj_gemm(const bf16* __restrict__ A,
                                                  const bf16* __restrict__ Bw,
                                                  const float* __restrict__ b_ih,
                                                  const float* __restrict__ b_hh,
                                                  float* __restrict__ C) {
  constexpr int K = 256, N = 1024;
  __shared__ __align__(16) bf16 As[128*32];
  __shared__ __align__(16) bf16 Bs[128*32];
  __shared__ float bias_s[128];
  const int bm = blockIdx.x >> 3;
  const int bn = blockIdx.x & 7;
  const int m0 = bm * 128, n0 = bn * 128;
  const int tid = threadIdx.x;
  if (tid < 128) bias_s[tid] = b_ih[n0 + tid] + b_hh[n0 + tid];
  const int w = tid >> 6, lane = tid & 63;
  const int wm = w >> 1, wn = w & 1;
  const int lr = lane & 15, lk = lane >> 4;
  f32x4 acc[4][4] = {};
  for (int kt = 0; kt < 8; ++kt) {
#pragma unroll
    for (int p = 0; p < 2; ++p) {
      int elem = p * 256 + tid;
      int row = elem >> 2, c = elem & 3;
      uint4 va = *reinterpret_cast<const uint4*>(A + (size_t)(m0 + row) * K + kt*32 + c*8);
      *reinterpret_cast<uint4*>((char*)As + row*64 + ((c ^ (row & 3)) * 16)) = va;
      uint4 vb = *reinterpret_cast<const uint4*>(Bw + (size_t)(n0 + row) * K + kt*32 + c*8);
      *reinterpret_cast<uint4*>((char*)Bs + row*64 + ((c ^ (row & 3)) * 16)) = vb;
    }
    __syncthreads();
    bf16x8 fa[4], fb[4];
#pragma unroll
    for (int f = 0; f < 4; ++f) {
      int ra = wm*64 + f*16 + lr;
      fa[f] = *reinterpret_cast<const bf16x8*>((char*)As + ra*64 + ((lk ^ (ra & 3)) * 16));
      int rb = wn*64 + f*16 + lr;
      fb[f] = *reinterpret_cast<const bf16x8*>((char*)Bs + rb*64 + ((lk ^ (rb & 3)) * 16));
    }
#pragma unroll
    for (int fi = 0; fi < 4; ++fi)
#pragma unroll
      for (int fj = 0; fj < 4; ++fj)
        acc[fi][fj] = __builtin_amdgcn_mfma_f32_16x16x32_bf16(fa[fi], fb[fj], acc[fi][fj], 0, 0, 0);
    __syncthreads();
  }
#pragma unroll
  for (int fi = 0; fi < 4; ++fi)
#pragma unroll
    for (int fj = 0; fj < 4; ++fj) {
      int col = n0 + wn*64 + fj*16 + lr;
      float bias = bias_s[wn*64 + fj*16 + lr];
#pragma unroll
      for (int v = 0; v < 4; ++v) {
        int row = m0 + wm*64 + fi*16 + lk*4 + v;
        C[(size_t)row * N + col] = acc[fi][fj][v] + bias;
      }
    }
}

// ---------------- recurrence (MFMA, dataflow exchange through y) ----------------
// 4 groups x 16 batches, 4 j-blocks per group (64 h each) = 16 blocks.
// h(t) is exchanged THROUGH the y output itself: y pre-memset to 0xFF (NaN
// sentinel); writers use relaxed agent-scope bypass stores; readers poll the
// exact dwords they need until != sentinel. T-indexed -> no WAR hazards, no
// counters, no fences, exactly one global round-trip per step.

__device__ __forceinline__ float fast_sigmoid(float x) {
  return __builtin_amdgcn_rcpf(1.f + __expf(-x));
}
__device__ __forceinline__ float fast_tanh(float x) {
  return 1.f - 2.f * __builtin_amdgcn_rcpf(__expf(2.f * x) + 1.f);
}

__global__ __launch_bounds__(256, 1) void lstm_rec(const float* __restrict__ xp,
                                                   const float* __restrict__ Whh,
                                                   float* __restrict__ out) {
  __shared__ __align__(16) bf16 h_s[2][16 * 256];  // parity-buffered, XOR swizzled
  const int tid = threadIdx.x;
  const int g  = blockIdx.x >> 2;
  const int jb = blockIdx.x & 3;
  const int w  = tid >> 6, l = tid & 63;
  const int lr = l & 15, lk = l >> 4;
  const int hidx = jb*64 + w*16 + lr;            // this lane's h index (n-col)

  // ---- preload W b-frags into VGPRs: bW[G][kk], n = G*256 + hidx, k = kk*32 + lk*8 + e
  bf16x8 bW[4][8];
#pragma unroll
  for (int G = 0; G < 4; ++G)
#pragma unroll
    for (int kk = 0; kk < 8; ++kk) {
      const float* wp = Whh + (size_t)(G*256 + hidx) * 256 + kk*32 + lk*8;
      float4 w0 = *reinterpret_cast<const float4*>(wp);
      float4 w1 = *reinterpret_cast<const float4*>(wp + 4);
      bf16x8 f = {(__bf16)w0.x, (__bf16)w0.y, (__bf16)w0.z, (__bf16)w0.w,
                  (__bf16)w1.x, (__bf16)w1.y, (__bf16)w1.z, (__bf16)w1.w};
      bW[G][kk] = f;
    }

  // zero h_s[0] (h0 = 0)
  {
    uint4 z = {0,0,0,0};
    uint4* p = reinterpret_cast<uint4*>(h_s[0]);
#pragma unroll
    for (int i = 0; i < 2; ++i) p[tid + i*256] = z;
  }

  float c[4] = {0.f, 0.f, 0.f, 0.f};
  // xp for t=0: xpv[G][v], batch m = lk*4+v, col = G*256 + hidx
  float xpv[4][4], xpn[4][4];
#pragma unroll
  for (int G = 0; G < 4; ++G)
#pragma unroll
    for (int v = 0; v < 4; ++v)
      xpv[G][v] = xp[((size_t)(g*16 + lk*4 + v) * Tz + 0) * 1024 + G*256 + hidx];

  const int bm_rd = tid >> 4;                    // exchange: batch row (0..15)
  const int k0_rd = (tid & 15) * 16;             // exchange: k start
  const int bg0 = g*16 + lk*4;
  // exchange source: y row (g*16+bm_rd), cols k0_rd..k0_rd+16
  const unsigned int* ysrc_base =
      (const unsigned int*)out + ((size_t)(g*16 + bm_rd) * Tz) * 256 + k0_rd;

  for (int t = 0; t < Tz; ++t) {
    bf16* hb = h_s[t & 1];
    if (t > 0) {
      // poll h(t-1) directly from y (cache-bypass loads), cvt, stage to LDS
      const unsigned int* src = ysrc_base + (size_t)(t - 1) * 256;
      unsigned int vv[16];
      for (;;) {
        unsigned int bad = 0;
#pragma unroll
        for (int e = 0; e < 16; ++e) {
          vv[e] = __hip_atomic_load(src + e, __ATOMIC_RELAXED, __HIP_MEMORY_SCOPE_AGENT);
          bad |= (vv[e] == SENT) ? 1u : 0u;
        }
        if (!bad) break;
      }
      float f0[16];
#pragma unroll
      for (int e = 0; e < 16; ++e) f0[e] = __uint_as_float(vv[e]);
      bf16x8 p0 = {(__bf16)f0[0], (__bf16)f0[1], (__bf16)f0[2], (__bf16)f0[3],
                   (__bf16)f0[4], (__bf16)f0[5], (__bf16)f0[6], (__bf16)f0[7]};
      bf16x8 p1 = {(__bf16)f0[8], (__bf16)f0[9], (__bf16)f0[10], (__bf16)f0[11],
                   (__bf16)f0[12], (__bf16)f0[13], (__bf16)f0[14], (__bf16)f0[15]};
      int ch0 = (tid & 15) * 2;
      char* dst = (char*)hb + bm_rd*512;
      *reinterpret_cast<bf16x8*>(dst + ((ch0 ^ (bm_rd & 7)) << 4)) = p0;
      *reinterpret_cast<bf16x8*>(dst + (((ch0+1) ^ (bm_rd & 7)) << 4)) = p1;
    }
    __syncthreads();
    if (t > 0) {
      // consume last iter's prefetch (waitcnt lands here, hidden by the poll)
#pragma unroll
      for (int G = 0; G < 4; ++G)
#pragma unroll
        for (int v = 0; v < 4; ++v) xpv[G][v] = xpn[G][v];
    }
    // a-frags from swizzled hb: lane reads h[batch=lr][k-chunk kk*4+lk]
    bf16x8 a[8];
#pragma unroll
    for (int kk = 0; kk < 8; ++kk) {
      int ch = kk*4 + lk;
      a[kk] = *reinterpret_cast<const bf16x8*>(
          (const char*)hb + lr*512 + ((ch ^ (lr & 7)) << 4));
    }
    // init acc from x_proj (includes both biases)
    f32x4 acc[4];
#pragma unroll
    for (int G = 0; G < 4; ++G) {
      acc[G][0] = xpv[G][0]; acc[G][1] = xpv[G][1];
      acc[G][2] = xpv[G][2]; acc[G][3] = xpv[G][3];
    }
    // prefetch next step's xp (consumed after next barrier)
    if (t < Tz - 1) {
#pragma unroll
      for (int G = 0; G < 4; ++G)
#pragma unroll
        for (int v = 0; v < 4; ++v)
          xpn[G][v] = xp[((size_t)(g*16 + lk*4 + v) * Tz + (t+1)) * 1024 + G*256 + hidx];
    }
    // gates = xp + h @ W^T : 32 MFMA
#pragma unroll
    for (int kk = 0; kk < 8; ++kk)
#pragma unroll
      for (int G = 0; G < 4; ++G)
        acc[G] = __builtin_amdgcn_mfma_f32_16x16x32_bf16(a[kk], bW[G][kk], acc[G], 0, 0, 0);

    // nonlinearity, fully in-register (batch m = lk*4+v)
#pragma unroll
    for (int v = 0; v < 4; ++v) {
      float ig = fast_sigmoid(acc[0][v]);
      float fg = fast_sigmoid(acc[1][v]);
      float gg = fast_tanh(acc[2][v]);
      float og = fast_sigmoid(acc[3][v]);
      float cn = fg * c[v] + ig * gg;
      c[v] = cn;
      float hv = og * fast_tanh(cn);
      // publish h(t) through y with a cache-bypassing store
      __hip_atomic_store((unsigned int*)&out[((size_t)(bg0 + v) * Tz + t) * 256 + hidx],
                         __float_as_uint(hv),
                         __ATOMIC_RELAXED, __HIP_MEMORY_SCOPE_AGENT);
      if (t == Tz - 1) {
        out[(size_t)YSZ + (bg0 + v) * 256 + hidx] = hv;
        out[(size_t)YSZ + 16384 + (bg0 + v) * 256 + hidx] = c[v];
      }
    }
  }
}

extern "C" void kernel_launch(void* const* d_in, const int* in_sizes, int n_in,
                              void* d_out, int out_size, void* d_ws, size_t ws_size,
                              hipStream_t stream) {
  const float* x    = (const float*)d_in[0];
  const float* W_ih = (const float*)d_in[1];
  const float* W_hh = (const float*)d_in[2];
  const float* b_ih = (const float*)d_in[3];
  const float* b_hh = (const float*)d_in[4];
  float* out = (float*)d_out;
  char* ws = (char*)d_ws;

  float*    xp    = (float*)(ws + XP_OFF);
  bf16*     xb    = (bf16*) (ws + XB_OFF);
  bf16*     wib   = (bf16*) (ws + WI_OFF);

  // y region = sentinel (NaN). Harness zeroes d_out before the call; we own it.
  hipMemsetAsync(out, 0xFF, (size_t)YSZ * 4, stream);
  cvt_f32_bf16<<<8192, 256, 0, stream>>>(x, xb, (Bz*Tz*Iz) / 4);
  cvt_f32_bf16<<<256, 256, 0, stream>>>(W_ih, wib, (G4z*Iz) / 4);
  xproj_gemm<<<2048, 256, 0, stream>>>(xb, wib, b_ih, b_hh, xp);
  lstm_rec<<<16, 256, 0, stream>>>(xp, W_hh, out);
}